// Round 9
// baseline (416.887 us; speedup 1.0000x reference)
//
#include <hip/hip_runtime.h>
#include <hip/hip_bf16.h>
#include <math.h>

#define N_NODES 50000
#define N_EDGES 800000
#define N_GRAPHS 64
#define IN_DIM 128
#define HID 32
#define HEADS 4
#define EDGE_DIM 8
#define OUT_DIM 10
#define HC 128          // HEADS*HID
#define NB 196          // ceil(N_NODES/256)
#define EBLK 3125       // ceil(N_EDGES/256)
#define G1BLK 782       // ceil(N_NODES/64)

__device__ __forceinline__ float leaky(float x){ return x >= 0.f ? x : 0.2f*x; }
__device__ __forceinline__ float elu_f(float x){ return x > 0.f ? x : __expf(x)-1.f; }

__device__ __forceinline__ float bf2f(unsigned short u){
  union { unsigned int i; float f; } v; v.i = ((unsigned int)u) << 16; return v.f;
}
__device__ __forceinline__ unsigned short f2bf(float f){
  union { float f; unsigned int i; } v; v.f = f;
  unsigned int r = v.i + 0x7FFF + ((v.i >> 16) & 1);
  return (unsigned short)(r >> 16);
}
__device__ __forceinline__ unsigned int pk2(float a, float b){
  return (unsigned int)f2bf(a) | ((unsigned int)f2bf(b) << 16);
}

// ---- degree histogram: standalone, 4 edges/thread, max occupancy ---------
__global__ __launch_bounds__(256) void k_hist(const int* __restrict__ dst, int* __restrict__ cnt){
  int i = blockIdx.x*256 + threadIdx.x;
  if (i*4 >= N_EDGES) return;
  int4 d4 = *(const int4*)&dst[i*4];
  atomicAdd(&cnt[d4.x], 1);
  atomicAdd(&cnt[d4.y], 1);
  atomicAdd(&cnt[d4.z], 1);
  atomicAdd(&cnt[d4.w], 1);
}

__global__ __launch_bounds__(256) void k_blocksum(const int* __restrict__ cnt, int* __restrict__ bsum){
  __shared__ int sh[256];
  int n = blockIdx.x*256 + threadIdx.x;
  sh[threadIdx.x] = (n < N_NODES) ? cnt[n] : 0;
  __syncthreads();
  for (int off = 128; off > 0; off >>= 1){
    if (threadIdx.x < off) sh[threadIdx.x] += sh[threadIdx.x + off];
    __syncthreads();
  }
  if (threadIdx.x == 0) bsum[blockIdx.x] = sh[0];
}

__global__ __launch_bounds__(256) void k_scanb(const int* __restrict__ bsum, int* __restrict__ bpre){
  __shared__ int sh[256];
  int t = threadIdx.x;
  int v = (t < NB) ? bsum[t] : 0;
  sh[t] = v; __syncthreads();
  for (int off = 1; off < 256; off <<= 1){
    int u = (t >= off) ? sh[t-off] : 0;
    __syncthreads();
    sh[t] += u;
    __syncthreads();
  }
  if (t < NB) bpre[t] = sh[t] - v;
}

__global__ __launch_bounds__(256) void k_rowptr(const int* __restrict__ cnt, const int* __restrict__ bpre,
    int* __restrict__ rowptr, int* __restrict__ wofs){
  __shared__ int sh[256];
  int t = threadIdx.x; int n = blockIdx.x*256 + t;
  int c = (n < N_NODES) ? cnt[n] : 0;
  sh[t] = c; __syncthreads();
  for (int off = 1; off < 256; off <<= 1){
    int u = (t >= off) ? sh[t-off] : 0;
    __syncthreads();
    sh[t] += u;
    __syncthreads();
  }
  int incl = sh[t];
  if (n < N_NODES){
    int rp = bpre[blockIdx.x] + incl - c;
    rowptr[n] = rp;
    wofs[n] = rp;
  }
  if (n == N_NODES-1) rowptr[N_NODES] = bpre[blockIdx.x] + incl;
}

// ---- GEMM1: standalone, conflict-free 50 KB LDS --------------------------
__global__ __launch_bounds__(256) void k_gemm1(const float* __restrict__ x, const float* __restrict__ W1,
    const float* __restrict__ as1, const float* __restrict__ ad1,
    unsigned short* __restrict__ h1b, float* __restrict__ als1, float* __restrict__ ald1){
  __shared__ float xs[8448];   // 64 rows x stride 132
  __shared__ float ws[4096];   // 32-k chunk, two 16-cg planes
  int t = threadIdx.x;
  int cg = t & 15, c8 = cg*8, qb = (t >> 4)*4;
  int base = blockIdx.x * 64;
  for (int i = t; i < 2048; i += 256){
    int node = base + (i >> 5);
    int col = (i & 31) * 4;
    float4 v = make_float4(0,0,0,0);
    if (node < N_NODES) v = *(const float4*)&x[node*IN_DIM + col];
    *(float4*)&xs[(i>>5)*132 + col] = v;
  }
  float acc[4][8];
  #pragma unroll
  for (int q = 0; q < 4; q++)
    #pragma unroll
    for (int i = 0; i < 8; i++) acc[q][i] = 0.f;

  for (int kb = 0; kb < 128; kb += 32){
    __syncthreads();
    for (int i = t; i < 1024; i += 256){
      int k = i >> 5, col4 = i & 31;
      int pcg = col4 >> 1, plane = col4 & 1;
      *(float4*)&ws[plane*2048 + k*64 + pcg*4] = *(const float4*)&W1[(kb+k)*128 + col4*4];
    }
    __syncthreads();
    #pragma unroll 4
    for (int k = 0; k < 32; k++){
      float4 w0 = *(float4*)&ws[k*64 + cg*4];
      float4 w1 = *(float4*)&ws[2048 + k*64 + cg*4];
      #pragma unroll
      for (int q = 0; q < 4; q++){
        float xv = xs[(qb + q)*132 + kb + k];
        acc[q][0] = fmaf(xv, w0.x, acc[q][0]);
        acc[q][1] = fmaf(xv, w0.y, acc[q][1]);
        acc[q][2] = fmaf(xv, w0.z, acc[q][2]);
        acc[q][3] = fmaf(xv, w0.w, acc[q][3]);
        acc[q][4] = fmaf(xv, w1.x, acc[q][4]);
        acc[q][5] = fmaf(xv, w1.y, acc[q][5]);
        acc[q][6] = fmaf(xv, w1.z, acc[q][6]);
        acc[q][7] = fmaf(xv, w1.w, acc[q][7]);
      }
    }
  }
  int head = cg >> 2;
  float asv[8], adv[8];
  #pragma unroll
  for (int i = 0; i < 8; i++){ asv[i] = as1[c8 + i]; adv[i] = ad1[c8 + i]; }
  #pragma unroll
  for (int q = 0; q < 4; q++){
    int n = base + qb + q;
    if (n >= N_NODES) continue;
    float sa = 0.f, sd = 0.f;
    #pragma unroll
    for (int i = 0; i < 8; i++){
      sa = fmaf(acc[q][i], asv[i], sa);
      sd = fmaf(acc[q][i], adv[i], sd);
    }
    sa += __shfl_xor(sa, 1); sd += __shfl_xor(sd, 1);
    sa += __shfl_xor(sa, 2); sd += __shfl_xor(sd, 2);
    uint4 pk;
    pk.x = pk2(acc[q][0], acc[q][1]);
    pk.y = pk2(acc[q][2], acc[q][3]);
    pk.z = pk2(acc[q][4], acc[q][5]);
    pk.w = pk2(acc[q][6], acc[q][7]);
    *(uint4*)&h1b[n*HC + c8] = pk;
    if ((cg & 3) == 0){ als1[n*4 + head] = sa; ald1[n*4 + head] = sd; }
  }
}

// ---- v1/v2 (We . att_e collapse) into smem[40] ---------------------------
__device__ __forceinline__ void v_smem(float* v,
    const float* __restrict__ We1, const float* __restrict__ ae1w,
    const float* __restrict__ We2, const float* __restrict__ ae2w){
  int t = threadIdx.x;
  if (t < 32){
    int d = t >> 2, h = t & 3;
    float s = 0.f;
    for (int c = 0; c < 32; c++) s = fmaf(We1[d*128 + h*32 + c], ae1w[h*32 + c], s);
    v[d*4 + h] = s;
  } else if (t < 40){
    int d = t - 32;
    float s = 0.f;
    for (int c = 0; c < 32; c++) s = fmaf(We2[d*32 + c], ae2w[c], s);
    v[32 + d] = s;
  }
  __syncthreads();
}

// ---- scatter: rec 16B {src, p1 x4 bf16, ae2 f32} + rec2 8B {ae1 x4 bf16} -
__global__ __launch_bounds__(256) void k_f2(const int* __restrict__ src, const int* __restrict__ dst,
    const float* __restrict__ eattr,
    const float* __restrict__ We1, const float* __restrict__ ae1w,
    const float* __restrict__ We2, const float* __restrict__ ae2w,
    const float* __restrict__ als1, const float* __restrict__ ald1,
    int* __restrict__ wofs, int4* __restrict__ rec, uint2* __restrict__ rec2){
  __shared__ float v[40];
  v_smem(v, We1, ae1w, We2, ae2w);
  int e = blockIdx.x*256 + threadIdx.x;
  if (e >= N_EDGES) return;
  int sv = src[e], d = dst[e];
  float4 x0 = *(const float4*)&eattr[e*8];
  float4 x1 = *(const float4*)&eattr[e*8+4];
  float ea[8] = {x0.x,x0.y,x0.z,x0.w,x1.x,x1.y,x1.z,x1.w};
  float4 r = make_float4(0,0,0,0);
  float r2 = 0.f;
  #pragma unroll
  for (int dd = 0; dd < 8; dd++){
    r.x = fmaf(ea[dd], v[dd*4+0], r.x);
    r.y = fmaf(ea[dd], v[dd*4+1], r.y);
    r.z = fmaf(ea[dd], v[dd*4+2], r.z);
    r.w = fmaf(ea[dd], v[dd*4+3], r.w);
    r2  = fmaf(ea[dd], v[32+dd], r2);
  }
  float4 as = *(const float4*)&als1[sv*4];
  float4 ad = *(const float4*)&ald1[d*4];
  float p0 = __expf(leaky(as.x + ad.x + r.x));
  float p1 = __expf(leaky(as.y + ad.y + r.y));
  float p2 = __expf(leaky(as.z + ad.z + r.z));
  float p3 = __expf(leaky(as.w + ad.w + r.w));
  int pos = atomicAdd(&wofs[d], 1);
  int4 rv;
  rv.x = sv;
  rv.y = (int)pk2(p0, p1);
  rv.z = (int)pk2(p2, p3);
  rv.w = __float_as_int(r2);
  rec[pos] = rv;
  rec2[pos] = make_uint2(pk2(r.x, r.y), pk2(r.z, r.w));
}

// ---- conv1: lean loop; sum_ae in-loop (rec2 sequential), pself inline ----
__global__ __launch_bounds__(256) void k_conv1(const int* __restrict__ rowptr, const int4* __restrict__ rec,
    const uint2* __restrict__ rec2, const float* __restrict__ als1, const float* __restrict__ ald1,
    const unsigned short* __restrict__ h1b, const float* __restrict__ b1,
    unsigned short* __restrict__ heb){
  int wv = threadIdx.x >> 6, l = threadIdx.x & 63;
  int n = blockIdx.x*4 + wv;
  if (n >= N_NODES) return;
  int c0 = l*2, h = l >> 4;
  int hs1 = (h & 1) * 16;
  unsigned int hsv = *(const unsigned int*)(h1b + n*HC + c0);
  float den = 0.f, sum_ae = 0.f;
  float2 acc = make_float2(0.f, 0.f);
  int r0 = rowptr[n], r1 = rowptr[n+1];
  int k = r0;
  for (; k + 2 <= r1; k += 2){
    int4 q0 = rec[k], q1 = rec[k+1];
    uint2 a0 = rec2[k], a1 = rec2[k+1];
    unsigned int w0 = (h & 2) ? (unsigned int)q0.z : (unsigned int)q0.y;
    unsigned int w1 = (h & 2) ? (unsigned int)q1.z : (unsigned int)q1.y;
    unsigned int e0 = (h & 2) ? a0.y : a0.x;
    unsigned int e1 = (h & 2) ? a1.y : a1.x;
    float p0 = bf2f((unsigned short)(w0 >> hs1));
    float p1 = bf2f((unsigned short)(w1 >> hs1));
    sum_ae += bf2f((unsigned short)(e0 >> hs1)) + bf2f((unsigned short)(e1 >> hs1));
    unsigned int hv0 = *(const unsigned int*)(h1b + q0.x*HC + c0);
    unsigned int hv1 = *(const unsigned int*)(h1b + q1.x*HC + c0);
    den += p0 + p1;
    acc.x = fmaf(p0, bf2f((unsigned short)hv0), acc.x);
    acc.y = fmaf(p0, bf2f((unsigned short)(hv0 >> 16)), acc.y);
    acc.x = fmaf(p1, bf2f((unsigned short)hv1), acc.x);
    acc.y = fmaf(p1, bf2f((unsigned short)(hv1 >> 16)), acc.y);
  }
  if (k < r1){
    int4 q = rec[k];
    uint2 a = rec2[k];
    unsigned int w = (h & 2) ? (unsigned int)q.z : (unsigned int)q.y;
    unsigned int e = (h & 2) ? a.y : a.x;
    float p = bf2f((unsigned short)(w >> hs1));
    sum_ae += bf2f((unsigned short)(e >> hs1));
    unsigned int hv = *(const unsigned int*)(h1b + q.x*HC + c0);
    den += p;
    acc.x = fmaf(p, bf2f((unsigned short)hv), acc.x);
    acc.y = fmaf(p, bf2f((unsigned short)(hv >> 16)), acc.y);
  }
  int cn = r1 - r0; if (cn < 1) cn = 1;
  float ps = __expf(leaky(als1[n*4 + h] + ald1[n*4 + h] + sum_ae / (float)cn));
  den += ps;
  acc.x = fmaf(ps, bf2f((unsigned short)hsv), acc.x);
  acc.y = fmaf(ps, bf2f((unsigned short)(hsv >> 16)), acc.y);
  float inv = 1.f / (den + 1e-16f);
  float o0 = elu_f(fmaf(acc.x, inv, b1[c0]));
  float o1 = elu_f(fmaf(acc.y, inv, b1[c0+1]));
  *(unsigned int*)(heb + n*HC + c0) = pk2(o0, o1);
}

// ---- GEMM2: h2 = h_elu@W2 [N,32] (bf16 in/out), als2/ald2 fp32 -----------
__global__ __launch_bounds__(256) void k_gemm2(const unsigned short* __restrict__ heb,
    const float* __restrict__ W2, const float* __restrict__ as2, const float* __restrict__ ad2,
    unsigned short* __restrict__ h2b, float* __restrict__ als2, float* __restrict__ ald2){
  __shared__ float ws[128*32];   // 16 KB full W2
  __shared__ float xs[16][128];  // 8 KB
  int t = threadIdx.x; int c = t & 31; int j = t >> 5;  // j: 0..7
  int base = blockIdx.x * 16;
  for (int i = t; i < 1024; i += 256)
    *(float4*)&ws[i*4] = *(const float4*)&W2[i*4];
  {
    int node = base + (t >> 4);
    int col = (t & 15) * 8;
    uint4 v = make_uint4(0,0,0,0);
    if (node < N_NODES) v = *(const uint4*)(heb + node*128 + col);
    float* xp = &xs[t>>4][col];
    xp[0] = bf2f((unsigned short)v.x); xp[1] = bf2f((unsigned short)(v.x>>16));
    xp[2] = bf2f((unsigned short)v.y); xp[3] = bf2f((unsigned short)(v.y>>16));
    xp[4] = bf2f((unsigned short)v.z); xp[5] = bf2f((unsigned short)(v.z>>16));
    xp[6] = bf2f((unsigned short)v.w); xp[7] = bf2f((unsigned short)(v.w>>16));
  }
  __syncthreads();
  float s0 = 0.f, s1 = 0.f;
  #pragma unroll 8
  for (int k = 0; k < 128; k++){
    float w = ws[k*32 + c];
    s0 = fmaf(xs[j*2][k],   w, s0);
    s1 = fmaf(xs[j*2+1][k], w, s1);
  }
  float a2c = as2[c], d2c = ad2[c];
  int n0 = base + j*2, n1 = n0 + 1;
  float sa0 = s0*a2c, sd0 = s0*d2c, sa1 = s1*a2c, sd1 = s1*d2c;
  #pragma unroll
  for (int off = 1; off < 32; off <<= 1){
    sa0 += __shfl_xor(sa0, off); sd0 += __shfl_xor(sd0, off);
    sa1 += __shfl_xor(sa1, off); sd1 += __shfl_xor(sd1, off);
  }
  if (n0 < N_NODES){ h2b[n0*32 + c] = f2bf(s0); if (c == 0){ als2[n0] = sa0; ald2[n0] = sd0; } }
  if (n1 < N_NODES){ h2b[n1*32 + c] = f2bf(s1); if (c == 0){ als2[n1] = sa1; ald2[n1] = sd1; } }
}

// ---- layer-2 coefficients: p2 CSR-ordered + pself2 (sum ae2 inline) ------
__global__ __launch_bounds__(256) void k_alpha2(const int* __restrict__ rowptr, const int* __restrict__ rec_i,
    const float* __restrict__ als2, const float* __restrict__ ald2,
    float* __restrict__ p2, float* __restrict__ pself2){
  int n = blockIdx.x*256 + threadIdx.x;
  if (n >= N_NODES) return;
  int r0 = rowptr[n], r1 = rowptr[n+1];
  float adn = ald2[n];
  float sum2 = 0.f;
  for (int k = r0; k < r1; k++){
    int sv = rec_i[k*4];
    float ae = __int_as_float(rec_i[k*4 + 3]);
    sum2 += ae;
    p2[k] = __expf(leaky(als2[sv] + adn + ae));
  }
  int cn = r1 - r0; if (cn < 1) cn = 1;
  pself2[n] = __expf(leaky(als2[n] + adn + sum2 / (float)cn));
}

// ---- conv2: half-wave edge split, exp-free loop --------------------------
__global__ __launch_bounds__(256) void k_conv2(const int* __restrict__ rowptr, const int* __restrict__ rec_i,
    const float* __restrict__ p2, const float* __restrict__ pself2,
    const unsigned short* __restrict__ h2b, const float* __restrict__ b2, float* __restrict__ out2){
  int wv = threadIdx.x >> 6, l = threadIdx.x & 63;
  int n = blockIdx.x*4 + wv;
  if (n >= N_NODES) return;
  int half = l >> 5, c = l & 31;
  int r0 = rowptr[n], r1 = rowptr[n+1];
  int h0 = (r1 - r0 + 1) >> 1;
  int ks = half ? r0 + h0 : r0;
  int ke = half ? r1 : r0 + h0;
  float den = 0.f, acc = 0.f;
  if (half == 0){
    float ps = pself2[n];
    den = ps;
    acc = ps * bf2f(h2b[n*32 + c]);
  }
  int k = ks;
  for (; k + 2 <= ke; k += 2){
    float pa = p2[k], pb = p2[k+1];
    int s0 = rec_i[k*4], s1 = rec_i[(k+1)*4];
    float hv0 = bf2f(h2b[s0*32 + c]);
    float hv1 = bf2f(h2b[s1*32 + c]);
    den += pa + pb;
    acc = fmaf(pa, hv0, acc);
    acc = fmaf(pb, hv1, acc);
  }
  if (k < ke){
    float pa = p2[k];
    int s0 = rec_i[k*4];
    den += pa;
    acc = fmaf(pa, bf2f(h2b[s0*32 + c]), acc);
  }
  den += __shfl_xor(den, 32);
  acc += __shfl_xor(acc, 32);
  float val = acc / (den + 1e-16f) + b2[c];
  if (half == 0) out2[n*32 + c] = elu_f(val);
}

// ---- global mean pool (batch is sorted) ----------------------------------
__global__ __launch_bounds__(256) void k_pool(const float* __restrict__ out2, const int* __restrict__ batch,
    float* __restrict__ gpool){
  int g = blockIdx.x;
  int a = 0, b = N_NODES;
  while (a < b){ int mid = (a + b) >> 1; if (batch[mid] < g) a = mid + 1; else b = mid; }
  int lo = a;
  a = lo; b = N_NODES;
  while (a < b){ int mid = (a + b) >> 1; if (batch[mid] < g + 1) a = mid + 1; else b = mid; }
  int hi = a;
  int t = threadIdx.x, c = t & 31, r = t >> 5;
  float s = 0.f;
  for (int n = lo + r; n < hi; n += 8) s += out2[n*32 + c];
  __shared__ float sh[256];
  sh[t] = s; __syncthreads();
  if (r == 0){
    for (int q = 1; q < 8; q++) s += sh[q*32 + c];
    int cg = hi - lo; if (cg < 1) cg = 1;
    gpool[g*32 + c] = s / (float)cg;
  }
}

// ---- MLP head ------------------------------------------------------------
__global__ __launch_bounds__(1024) void k_mlp(const float* __restrict__ gpool, const float* __restrict__ W3,
    const float* __restrict__ b3, const float* __restrict__ W4, const float* __restrict__ b4,
    float* __restrict__ out){
  __shared__ float z[64*16];
  int t = threadIdx.x;
  {
    int g = t >> 4, jj = t & 15;
    float s = b3[jj];
    #pragma unroll
    for (int c = 0; c < 32; c++) s = fmaf(gpool[g*32 + c], W3[c*16 + jj], s);
    z[t] = fmaxf(s, 0.f);
  }
  __syncthreads();
  if (t < 640){
    int g = t / 10, o = t - g*10;
    float s = b4[o];
    #pragma unroll
    for (int jj = 0; jj < 16; jj++) s = fmaf(z[g*16 + jj], W4[jj*10 + o], s);
    out[t] = s;
  }
}

extern "C" void kernel_launch(void* const* d_in, const int* in_sizes, int n_in,
                              void* d_out, int out_size, void* d_ws, size_t ws_size,
                              hipStream_t stream) {
  (void)in_sizes; (void)n_in; (void)out_size; (void)ws_size;
  const float* x     = (const float*)d_in[0];
  const int*   ei    = (const int*)  d_in[1];
  const float* eattr = (const float*)d_in[2];
  const int*   batch = (const int*)  d_in[3];
  const float* W1    = (const float*)d_in[4];
  const float* as1   = (const float*)d_in[5];
  const float* ad1   = (const float*)d_in[6];
  const float* We1   = (const float*)d_in[7];
  const float* ae1w  = (const float*)d_in[8];
  const float* b1    = (const float*)d_in[9];
  const float* W2    = (const float*)d_in[10];
  const float* as2   = (const float*)d_in[11];
  const float* ad2   = (const float*)d_in[12];
  const float* We2   = (const float*)d_in[13];
  const float* ae2w  = (const float*)d_in[14];
  const float* b2    = (const float*)d_in[15];
  const float* W3    = (const float*)d_in[16];
  const float* b3    = (const float*)d_in[17];
  const float* W4    = (const float*)d_in[18];
  const float* b4    = (const float*)d_in[19];
  float* out = (float*)d_out;
  const int* src  = ei;
  const int* dstp = ei + N_EDGES;

  char* p = (char*)d_ws;
  auto alloc = [&](size_t bytes)->void*{ void* r = (void*)p; p += (bytes + 255) & ~(size_t)255; return r; };
  int*    cnt      = (int*)   alloc(4*N_NODES);
  size_t  zero_bytes = (size_t)(p - (char*)d_ws);   // only cnt needs zeroing
  int*    wofs     = (int*)   alloc(4*N_NODES);
  int*    rowptr   = (int*)   alloc(4*(N_NODES+1));
  int*    bsum     = (int*)   alloc(4*NB);
  int*    bpre     = (int*)   alloc(4*NB);
  int4*   rec      = (int4*)  alloc(16*N_EDGES);
  uint2*  rec2     = (uint2*) alloc(8*N_EDGES);
  float*  p2       = (float*) alloc(4*N_EDGES);
  unsigned short* h1b  = (unsigned short*)alloc(2*N_NODES*HC);
  float*  als1     = (float*) alloc(16*N_NODES);
  float*  ald1     = (float*) alloc(16*N_NODES);
  float*  pself2   = (float*) alloc(4*N_NODES);
  unsigned short* heb  = (unsigned short*)alloc(2*N_NODES*HC);
  unsigned short* h2b  = (unsigned short*)alloc(2*N_NODES*HID);
  float*  als2     = (float*) alloc(4*N_NODES);
  float*  ald2     = (float*) alloc(4*N_NODES);
  float*  out2     = (float*) alloc(4*N_NODES*HID);
  float*  gpool    = (float*) alloc(4*N_GRAPHS*HID);

  hipMemsetAsync(d_ws, 0, zero_bytes, stream);
  k_hist    <<<(N_EDGES/4 + 255)/256, 256, 0, stream>>>(dstp, cnt);
  k_blocksum<<<NB,      256, 0, stream>>>(cnt, bsum);
  k_scanb   <<<1,       256, 0, stream>>>(bsum, bpre);
  k_rowptr  <<<NB,      256, 0, stream>>>(cnt, bpre, rowptr, wofs);
  k_gemm1   <<<G1BLK,   256, 0, stream>>>(x, W1, as1, ad1, h1b, als1, ald1);
  k_f2      <<<EBLK,    256, 0, stream>>>(src, dstp, eattr, We1, ae1w, We2, ae2w,
                                          als1, ald1, wofs, rec, rec2);
  k_conv1   <<<(N_NODES+3)/4, 256, 0, stream>>>(rowptr, rec, rec2, als1, ald1, h1b, b1, heb);
  k_gemm2   <<<(N_NODES+15)/16, 256, 0, stream>>>(heb, W2, as2, ad2, h2b, als2, ald2);
  k_alpha2  <<<NB,      256, 0, stream>>>(rowptr, (const int*)rec, als2, ald2, p2, pself2);
  k_conv2   <<<(N_NODES+3)/4, 256, 0, stream>>>(rowptr, (const int*)rec, p2, pself2, h2b, b2, out2);
  k_pool    <<<N_GRAPHS, 256, 0, stream>>>(out2, batch, gpool);
  k_mlp     <<<1,      1024, 0, stream>>>(gpool, W3, b3, W4, b4, out);
}

// Round 10
// 387.701 us; speedup vs baseline: 1.0753x; 1.0753x over previous
//
#include <hip/hip_runtime.h>
#include <hip/hip_bf16.h>
#include <math.h>

#define N_NODES 50000
#define N_EDGES 800000
#define N_GRAPHS 64
#define IN_DIM 128
#define HID 32
#define HEADS 4
#define EDGE_DIM 8
#define OUT_DIM 10
#define HC 128          // HEADS*HID
#define NB 196          // ceil(N_NODES/256)
#define EBLK 3125       // ceil(N_EDGES/256)
#define G1BLK 782       // ceil(N_NODES/64)

__device__ __forceinline__ float leaky(float x){ return x >= 0.f ? x : 0.2f*x; }
__device__ __forceinline__ float elu_f(float x){ return x > 0.f ? x : __expf(x)-1.f; }

__device__ __forceinline__ float bf2f(unsigned short u){
  union { unsigned int i; float f; } v; v.i = ((unsigned int)u) << 16; return v.f;
}
__device__ __forceinline__ unsigned short f2bf(float f){
  union { float f; unsigned int i; } v; v.f = f;
  unsigned int r = v.i + 0x7FFF + ((v.i >> 16) & 1);
  return (unsigned short)(r >> 16);
}
__device__ __forceinline__ unsigned int pk2(float a, float b){
  return (unsigned int)f2bf(a) | ((unsigned int)f2bf(b) << 16);
}

// ---- GEMM1 + degree histogram fused --------------------------------------
// Each block fires 1024 fire-and-forget atomics BEFORE LDS staging; their
// latency hides under the FMA loop (no extra LDS, occupancy unchanged).
// 782 blocks x 1024 edges >= 800k.
__global__ __launch_bounds__(256) void k_g1h(const int* __restrict__ dst, int* __restrict__ cnt,
    const float* __restrict__ x, const float* __restrict__ W1,
    const float* __restrict__ as1, const float* __restrict__ ad1,
    unsigned short* __restrict__ h1b, float* __restrict__ als1, float* __restrict__ ald1){
  __shared__ float xs[8448];   // 64 rows x stride 132 (2-way alias = free)
  __shared__ float ws[4096];   // 32-k chunk, two 16-cg planes (conflict-free)
  int t = threadIdx.x;
  {
    int e0 = blockIdx.x*1024 + t;
    #pragma unroll
    for (int i = 0; i < 4; i++){
      int e = e0 + i*256;
      if (e < N_EDGES) atomicAdd(&cnt[dst[e]], 1);
    }
  }
  int cg = t & 15, c8 = cg*8, qb = (t >> 4)*4;
  int base = blockIdx.x * 64;
  for (int i = t; i < 2048; i += 256){
    int node = base + (i >> 5);
    int col = (i & 31) * 4;
    float4 v = make_float4(0,0,0,0);
    if (node < N_NODES) v = *(const float4*)&x[node*IN_DIM + col];
    *(float4*)&xs[(i>>5)*132 + col] = v;
  }
  float acc[4][8];
  #pragma unroll
  for (int q = 0; q < 4; q++)
    #pragma unroll
    for (int i = 0; i < 8; i++) acc[q][i] = 0.f;

  for (int kb = 0; kb < 128; kb += 32){
    __syncthreads();
    for (int i = t; i < 1024; i += 256){
      int k = i >> 5, col4 = i & 31;
      int pcg = col4 >> 1, plane = col4 & 1;
      *(float4*)&ws[plane*2048 + k*64 + pcg*4] = *(const float4*)&W1[(kb+k)*128 + col4*4];
    }
    __syncthreads();
    #pragma unroll 4
    for (int k = 0; k < 32; k++){
      float4 w0 = *(float4*)&ws[k*64 + cg*4];
      float4 w1 = *(float4*)&ws[2048 + k*64 + cg*4];
      #pragma unroll
      for (int q = 0; q < 4; q++){
        float xv = xs[(qb + q)*132 + kb + k];
        acc[q][0] = fmaf(xv, w0.x, acc[q][0]);
        acc[q][1] = fmaf(xv, w0.y, acc[q][1]);
        acc[q][2] = fmaf(xv, w0.z, acc[q][2]);
        acc[q][3] = fmaf(xv, w0.w, acc[q][3]);
        acc[q][4] = fmaf(xv, w1.x, acc[q][4]);
        acc[q][5] = fmaf(xv, w1.y, acc[q][5]);
        acc[q][6] = fmaf(xv, w1.z, acc[q][6]);
        acc[q][7] = fmaf(xv, w1.w, acc[q][7]);
      }
    }
  }
  int head = cg >> 2;
  float asv[8], adv[8];
  #pragma unroll
  for (int i = 0; i < 8; i++){ asv[i] = as1[c8 + i]; adv[i] = ad1[c8 + i]; }
  #pragma unroll
  for (int q = 0; q < 4; q++){
    int n = base + qb + q;
    if (n >= N_NODES) continue;
    float sa = 0.f, sd = 0.f;
    #pragma unroll
    for (int i = 0; i < 8; i++){
      sa = fmaf(acc[q][i], asv[i], sa);
      sd = fmaf(acc[q][i], adv[i], sd);
    }
    sa += __shfl_xor(sa, 1); sd += __shfl_xor(sd, 1);
    sa += __shfl_xor(sa, 2); sd += __shfl_xor(sd, 2);
    uint4 pk;
    pk.x = pk2(acc[q][0], acc[q][1]);
    pk.y = pk2(acc[q][2], acc[q][3]);
    pk.z = pk2(acc[q][4], acc[q][5]);
    pk.w = pk2(acc[q][6], acc[q][7]);
    *(uint4*)&h1b[n*HC + c8] = pk;
    if ((cg & 3) == 0){ als1[n*4 + head] = sa; ald1[n*4 + head] = sd; }
  }
}

__global__ __launch_bounds__(256) void k_blocksum(const int* __restrict__ cnt, int* __restrict__ bsum){
  __shared__ int sh[256];
  int n = blockIdx.x*256 + threadIdx.x;
  sh[threadIdx.x] = (n < N_NODES) ? cnt[n] : 0;
  __syncthreads();
  for (int off = 128; off > 0; off >>= 1){
    if (threadIdx.x < off) sh[threadIdx.x] += sh[threadIdx.x + off];
    __syncthreads();
  }
  if (threadIdx.x == 0) bsum[blockIdx.x] = sh[0];
}

__global__ __launch_bounds__(256) void k_scanb(const int* __restrict__ bsum, int* __restrict__ bpre){
  __shared__ int sh[256];
  int t = threadIdx.x;
  int v = (t < NB) ? bsum[t] : 0;
  sh[t] = v; __syncthreads();
  for (int off = 1; off < 256; off <<= 1){
    int u = (t >= off) ? sh[t-off] : 0;
    __syncthreads();
    sh[t] += u;
    __syncthreads();
  }
  if (t < NB) bpre[t] = sh[t] - v;
}

__global__ __launch_bounds__(256) void k_rowptr(const int* __restrict__ cnt, const int* __restrict__ bpre,
    int* __restrict__ rowptr, int* __restrict__ wofs){
  __shared__ int sh[256];
  int t = threadIdx.x; int n = blockIdx.x*256 + t;
  int c = (n < N_NODES) ? cnt[n] : 0;
  sh[t] = c; __syncthreads();
  for (int off = 1; off < 256; off <<= 1){
    int u = (t >= off) ? sh[t-off] : 0;
    __syncthreads();
    sh[t] += u;
    __syncthreads();
  }
  int incl = sh[t];
  if (n < N_NODES){
    int rp = bpre[blockIdx.x] + incl - c;
    rowptr[n] = rp;
    wofs[n] = rp;
  }
  if (n == N_NODES-1) rowptr[N_NODES] = bpre[blockIdx.x] + incl;
}

// ---- v1/v2 (We . att_e collapse) into smem[40] ---------------------------
__device__ __forceinline__ void v_smem(float* v,
    const float* __restrict__ We1, const float* __restrict__ ae1w,
    const float* __restrict__ We2, const float* __restrict__ ae2w){
  int t = threadIdx.x;
  if (t < 32){
    int d = t >> 2, h = t & 3;
    float s = 0.f;
    for (int c = 0; c < 32; c++) s = fmaf(We1[d*128 + h*32 + c], ae1w[h*32 + c], s);
    v[d*4 + h] = s;
  } else if (t < 40){
    int d = t - 32;
    float s = 0.f;
    for (int c = 0; c < 32; c++) s = fmaf(We2[d*32 + c], ae2w[c], s);
    v[32 + d] = s;
  }
  __syncthreads();
}

// ---- scatter: rec 16B {src, p1 x4 bf16, ae2 f32} + rec2 8B {ae1 x4 bf16} -
__global__ __launch_bounds__(256) void k_f2(const int* __restrict__ src, const int* __restrict__ dst,
    const float* __restrict__ eattr,
    const float* __restrict__ We1, const float* __restrict__ ae1w,
    const float* __restrict__ We2, const float* __restrict__ ae2w,
    const float* __restrict__ als1, const float* __restrict__ ald1,
    int* __restrict__ wofs, int4* __restrict__ rec, uint2* __restrict__ rec2){
  __shared__ float v[40];
  v_smem(v, We1, ae1w, We2, ae2w);
  int e = blockIdx.x*256 + threadIdx.x;
  if (e >= N_EDGES) return;
  int sv = src[e], d = dst[e];
  float4 x0 = *(const float4*)&eattr[e*8];
  float4 x1 = *(const float4*)&eattr[e*8+4];
  float ea[8] = {x0.x,x0.y,x0.z,x0.w,x1.x,x1.y,x1.z,x1.w};
  float4 r = make_float4(0,0,0,0);
  float r2 = 0.f;
  #pragma unroll
  for (int dd = 0; dd < 8; dd++){
    r.x = fmaf(ea[dd], v[dd*4+0], r.x);
    r.y = fmaf(ea[dd], v[dd*4+1], r.y);
    r.z = fmaf(ea[dd], v[dd*4+2], r.z);
    r.w = fmaf(ea[dd], v[dd*4+3], r.w);
    r2  = fmaf(ea[dd], v[32+dd], r2);
  }
  float4 as = *(const float4*)&als1[sv*4];
  float4 ad = *(const float4*)&ald1[d*4];
  float p0 = __expf(leaky(as.x + ad.x + r.x));
  float p1 = __expf(leaky(as.y + ad.y + r.y));
  float p2 = __expf(leaky(as.z + ad.z + r.z));
  float p3 = __expf(leaky(as.w + ad.w + r.w));
  int pos = atomicAdd(&wofs[d], 1);
  int4 rv;
  rv.x = sv;
  rv.y = (int)pk2(p0, p1);
  rv.z = (int)pk2(p2, p3);
  rv.w = __float_as_int(r2);
  rec[pos] = rv;
  rec2[pos] = make_uint2(pk2(r.x, r.y), pk2(r.z, r.w));
}

// ---- conv1 + GEMM2 fused -------------------------------------------------
// conv1's wave holds the full 128-vector h_elu for its node -> round-trip
// through LDS (he 2KB/block) against W2 staged in LDS (16KB) computes
// h2/als2/ald2 in-place. heb global buffer eliminated (25.6 MB traffic),
// gemm2 launch eliminated. LDS 18KB -> 8 blocks/CU, occupancy unchanged.
__global__ __launch_bounds__(256) void k_c1g2(const int* __restrict__ rowptr, const int4* __restrict__ rec,
    const uint2* __restrict__ rec2, const float* __restrict__ als1, const float* __restrict__ ald1,
    const unsigned short* __restrict__ h1b, const float* __restrict__ b1,
    const float* __restrict__ W2, const float* __restrict__ as2, const float* __restrict__ ad2,
    unsigned short* __restrict__ h2b, float* __restrict__ als2, float* __restrict__ ald2){
  __shared__ float w2s[128*32];  // 16 KB
  __shared__ float he[4][128];   // 2 KB (per-wave region)
  int t = threadIdx.x;
  for (int i = t; i < 1024; i += 256)
    *(float4*)&w2s[i*4] = *(const float4*)&W2[i*4];
  __syncthreads();
  int wv = t >> 6, l = t & 63;
  int n = blockIdx.x*4 + wv;
  if (n >= N_NODES) return;
  int c0 = l*2, h = l >> 4;
  int hs1 = (h & 1) * 16;
  unsigned int hsv = *(const unsigned int*)(h1b + n*HC + c0);
  float den = 0.f, sum_ae = 0.f;
  float2 acc = make_float2(0.f, 0.f);
  int r0 = rowptr[n], r1 = rowptr[n+1];
  int k = r0;
  for (; k + 2 <= r1; k += 2){
    int4 q0 = rec[k], q1 = rec[k+1];
    uint2 a0 = rec2[k], a1 = rec2[k+1];
    unsigned int w0 = (h & 2) ? (unsigned int)q0.z : (unsigned int)q0.y;
    unsigned int w1 = (h & 2) ? (unsigned int)q1.z : (unsigned int)q1.y;
    unsigned int e0 = (h & 2) ? a0.y : a0.x;
    unsigned int e1 = (h & 2) ? a1.y : a1.x;
    float p0 = bf2f((unsigned short)(w0 >> hs1));
    float p1 = bf2f((unsigned short)(w1 >> hs1));
    sum_ae += bf2f((unsigned short)(e0 >> hs1)) + bf2f((unsigned short)(e1 >> hs1));
    unsigned int hv0 = *(const unsigned int*)(h1b + q0.x*HC + c0);
    unsigned int hv1 = *(const unsigned int*)(h1b + q1.x*HC + c0);
    den += p0 + p1;
    acc.x = fmaf(p0, bf2f((unsigned short)hv0), acc.x);
    acc.y = fmaf(p0, bf2f((unsigned short)(hv0 >> 16)), acc.y);
    acc.x = fmaf(p1, bf2f((unsigned short)hv1), acc.x);
    acc.y = fmaf(p1, bf2f((unsigned short)(hv1 >> 16)), acc.y);
  }
  if (k < r1){
    int4 q = rec[k];
    uint2 a = rec2[k];
    unsigned int w = (h & 2) ? (unsigned int)q.z : (unsigned int)q.y;
    unsigned int e = (h & 2) ? a.y : a.x;
    float p = bf2f((unsigned short)(w >> hs1));
    sum_ae += bf2f((unsigned short)(e >> hs1));
    unsigned int hv = *(const unsigned int*)(h1b + q.x*HC + c0);
    den += p;
    acc.x = fmaf(p, bf2f((unsigned short)hv), acc.x);
    acc.y = fmaf(p, bf2f((unsigned short)(hv >> 16)), acc.y);
  }
  int cn = r1 - r0; if (cn < 1) cn = 1;
  float ps = __expf(leaky(als1[n*4 + h] + ald1[n*4 + h] + sum_ae / (float)cn));
  den += ps;
  acc.x = fmaf(ps, bf2f((unsigned short)hsv), acc.x);
  acc.y = fmaf(ps, bf2f((unsigned short)(hsv >> 16)), acc.y);
  float inv = 1.f / (den + 1e-16f);
  float o0 = elu_f(fmaf(acc.x, inv, b1[c0]));
  float o1 = elu_f(fmaf(acc.y, inv, b1[c0+1]));
  // gemm2 in-place: stage h_elu to per-wave LDS, dot against W2
  *(float2*)&he[wv][c0] = make_float2(o0, o1);
  // wave-internal LDS write->read; compiler inserts lgkmcnt wait
  int c = l & 31, kh = (l >> 5) * 64;
  float s = 0.f;
  #pragma unroll 8
  for (int kk = 0; kk < 64; kk++)
    s = fmaf(he[wv][kh + kk], w2s[(kh + kk)*32 + c], s);
  s += __shfl_xor(s, 32);
  if (l < 32){
    h2b[n*32 + c] = f2bf(s);
    float sa = s * as2[c], sd = s * ad2[c];
    #pragma unroll
    for (int off = 1; off < 32; off <<= 1){
      sa += __shfl_xor(sa, off);
      sd += __shfl_xor(sd, off);
    }
    if (c == 0){ als2[n] = sa; ald2[n] = sd; }
  }
}

// ---- conv2: half-wave edge split, inline alpha (exp + als2 gather) -------
__global__ __launch_bounds__(256) void k_conv2(const int* __restrict__ rowptr, const int4* __restrict__ rec,
    const float* __restrict__ als2, const float* __restrict__ ald2,
    const unsigned short* __restrict__ h2b, const float* __restrict__ b2, float* __restrict__ out2){
  int wv = threadIdx.x >> 6, l = threadIdx.x & 63;
  int n = blockIdx.x*4 + wv;
  if (n >= N_NODES) return;
  int half = l >> 5, c = l & 31;
  float ad = ald2[n];
  int r0 = rowptr[n], r1 = rowptr[n+1];
  int h0 = (r1 - r0 + 1) >> 1;
  int ks = half ? r0 + h0 : r0;
  int ke = half ? r1 : r0 + h0;
  float den = 0.f, acc = 0.f, sum_ae = 0.f;
  int k = ks;
  for (; k + 2 <= ke; k += 2){
    int4 q0 = rec[k], q1 = rec[k+1];
    float ae_0 = __int_as_float(q0.w), ae_1 = __int_as_float(q1.w);
    float as_0 = als2[q0.x], as_1 = als2[q1.x];
    float hv0 = bf2f(h2b[q0.x*32 + c]);
    float hv1 = bf2f(h2b[q1.x*32 + c]);
    float p0 = __expf(leaky(as_0 + ad + ae_0));
    float p1 = __expf(leaky(as_1 + ad + ae_1));
    sum_ae += ae_0 + ae_1;
    den += p0 + p1;
    acc = fmaf(p0, hv0, acc);
    acc = fmaf(p1, hv1, acc);
  }
  if (k < ke){
    int4 q = rec[k];
    float aev = __int_as_float(q.w);
    float p = __expf(leaky(als2[q.x] + ad + aev));
    sum_ae += aev; den += p;
    acc = fmaf(p, bf2f(h2b[q.x*32 + c]), acc);
  }
  den += __shfl_xor(den, 32);
  acc += __shfl_xor(acc, 32);
  sum_ae += __shfl_xor(sum_ae, 32);
  int cn = r1 - r0; if (cn < 1) cn = 1;
  float ps = __expf(leaky(als2[n] + ad + sum_ae / (float)cn));
  den += ps;
  acc = fmaf(ps, bf2f(h2b[n*32 + c]), acc);
  float val = acc / (den + 1e-16f) + b2[c];
  if (half == 0) out2[n*32 + c] = elu_f(val);
}

// ---- global mean pool (batch is sorted) ----------------------------------
__global__ __launch_bounds__(256) void k_pool(const float* __restrict__ out2, const int* __restrict__ batch,
    float* __restrict__ gpool){
  int g = blockIdx.x;
  int a = 0, b = N_NODES;
  while (a < b){ int mid = (a + b) >> 1; if (batch[mid] < g) a = mid + 1; else b = mid; }
  int lo = a;
  a = lo; b = N_NODES;
  while (a < b){ int mid = (a + b) >> 1; if (batch[mid] < g + 1) a = mid + 1; else b = mid; }
  int hi = a;
  int t = threadIdx.x, c = t & 31, r = t >> 5;
  float s = 0.f;
  for (int n = lo + r; n < hi; n += 8) s += out2[n*32 + c];
  __shared__ float sh[256];
  sh[t] = s; __syncthreads();
  if (r == 0){
    for (int q = 1; q < 8; q++) s += sh[q*32 + c];
    int cg = hi - lo; if (cg < 1) cg = 1;
    gpool[g*32 + c] = s / (float)cg;
  }
}

// ---- MLP head ------------------------------------------------------------
__global__ __launch_bounds__(1024) void k_mlp(const float* __restrict__ gpool, const float* __restrict__ W3,
    const float* __restrict__ b3, const float* __restrict__ W4, const float* __restrict__ b4,
    float* __restrict__ out){
  __shared__ float z[64*16];
  int t = threadIdx.x;
  {
    int g = t >> 4, jj = t & 15;
    float s = b3[jj];
    #pragma unroll
    for (int c = 0; c < 32; c++) s = fmaf(gpool[g*32 + c], W3[c*16 + jj], s);
    z[t] = fmaxf(s, 0.f);
  }
  __syncthreads();
  if (t < 640){
    int g = t / 10, o = t - g*10;
    float s = b4[o];
    #pragma unroll
    for (int jj = 0; jj < 16; jj++) s = fmaf(z[g*16 + jj], W4[jj*10 + o], s);
    out[t] = s;
  }
}

extern "C" void kernel_launch(void* const* d_in, const int* in_sizes, int n_in,
                              void* d_out, int out_size, void* d_ws, size_t ws_size,
                              hipStream_t stream) {
  (void)in_sizes; (void)n_in; (void)out_size; (void)ws_size;
  const float* x     = (const float*)d_in[0];
  const int*   ei    = (const int*)  d_in[1];
  const float* eattr = (const float*)d_in[2];
  const int*   batch = (const int*)  d_in[3];
  const float* W1    = (const float*)d_in[4];
  const float* as1   = (const float*)d_in[5];
  const float* ad1   = (const float*)d_in[6];
  const float* We1   = (const float*)d_in[7];
  const float* ae1w  = (const float*)d_in[8];
  const float* b1    = (const float*)d_in[9];
  const float* W2    = (const float*)d_in[10];
  const float* as2   = (const float*)d_in[11];
  const float* ad2   = (const float*)d_in[12];
  const float* We2   = (const float*)d_in[13];
  const float* ae2w  = (const float*)d_in[14];
  const float* b2    = (const float*)d_in[15];
  const float* W3    = (const float*)d_in[16];
  const float* b3    = (const float*)d_in[17];
  const float* W4    = (const float*)d_in[18];
  const float* b4    = (const float*)d_in[19];
  float* out = (float*)d_out;
  const int* src  = ei;
  const int* dstp = ei + N_EDGES;

  char* p = (char*)d_ws;
  auto alloc = [&](size_t bytes)->void*{ void* r = (void*)p; p += (bytes + 255) & ~(size_t)255; return r; };
  int*    cnt      = (int*)   alloc(4*N_NODES);
  size_t  zero_bytes = (size_t)(p - (char*)d_ws);   // only cnt needs zeroing
  int*    wofs     = (int*)   alloc(4*N_NODES);
  int*    rowptr   = (int*)   alloc(4*(N_NODES+1));
  int*    bsum     = (int*)   alloc(4*NB);
  int*    bpre     = (int*)   alloc(4*NB);
  int4*   rec      = (int4*)  alloc(16*N_EDGES);
  uint2*  rec2     = (uint2*) alloc(8*N_EDGES);
  unsigned short* h1b  = (unsigned short*)alloc(2*N_NODES*HC);
  float*  als1     = (float*) alloc(16*N_NODES);
  float*  ald1     = (float*) alloc(16*N_NODES);
  unsigned short* h2b  = (unsigned short*)alloc(2*N_NODES*HID);
  float*  als2     = (float*) alloc(4*N_NODES);
  float*  ald2     = (float*) alloc(4*N_NODES);
  float*  out2     = (float*) alloc(4*N_NODES*HID);
  float*  gpool    = (float*) alloc(4*N_GRAPHS*HID);

  hipMemsetAsync(d_ws, 0, zero_bytes, stream);
  k_g1h     <<<G1BLK,   256, 0, stream>>>(dstp, cnt, x, W1, as1, ad1, h1b, als1, ald1);
  k_blocksum<<<NB,      256, 0, stream>>>(cnt, bsum);
  k_scanb   <<<1,       256, 0, stream>>>(bsum, bpre);
  k_rowptr  <<<NB,      256, 0, stream>>>(cnt, bpre, rowptr, wofs);
  k_f2      <<<EBLK,    256, 0, stream>>>(src, dstp, eattr, We1, ae1w, We2, ae2w,
                                          als1, ald1, wofs, rec, rec2);
  k_c1g2    <<<(N_NODES+3)/4, 256, 0, stream>>>(rowptr, rec, rec2, als1, ald1, h1b, b1,
                                                W2, as2, ad2, h2b, als2, ald2);
  k_conv2   <<<(N_NODES+3)/4, 256, 0, stream>>>(rowptr, rec, als2, ald2, h2b, b2, out2);
  k_pool    <<<N_GRAPHS, 256, 0, stream>>>(out2, batch, gpool);
  k_mlp     <<<1,      1024, 0, stream>>>(gpool, W3, b3, W4, b4, out);
}